// Round 3
// baseline (45.289 us; speedup 1.0000x reference)
//
#include <hip/hip_runtime.h>

// NNLoss: min over 5x5 shifted neighborhoods of channel-summed L1 distance,
// then global mean. B=16, C=3, H=W=512, fp32.
// R3: 8px/thread, float4 staging with row-clamp+select, aligned LDS reads via
// 4-col left pad, min3 tree.

#define PADV (-10000.0f)

constexpr int Bn = 16, Cn = 3, Hn = 512, Wn = 512;
constexpr long PLANE = (long)Hn * Wn;                  // 262144

constexpr int TW = 128, TH = 16;                       // output tile per block
constexpr int GW = 136;                                // LDS cols: global w0-4 .. w0+131
constexpr int GH = TH + 4;                             // 20 rows: h0-2 .. h0+17
constexpr int BLOCK = 256;
constexpr int TILES_W = Wn / TW;                       // 4
constexpr int TILES_H = Hn / TH;                       // 32
constexpr int NBLOCKS = Bn * TILES_H * TILES_W;        // 2048
constexpr int BODY_F4 = GH * 32;                       // 640 float4 per channel (cols 4..131)

__global__ __launch_bounds__(BLOCK, 4) void nnloss_main(
    const float* __restrict__ pred, const float* __restrict__ gt,
    float* __restrict__ partial) {
  const int bid = blockIdx.x;
  const int tw = bid & (TILES_W - 1);
  const int th = (bid >> 2) & (TILES_H - 1);
  const int b = bid >> 7;
  const int w0 = tw * TW;
  const int h0 = th * TH;

  __shared__ __align__(16) float tile[Cn][GH][GW];     // 32,640 B

  const float* gb = gt + (long)b * Cn * PLANE;

  // ---- stage body: LDS cols [4,132) = global cols [w0, w0+128), float4 ----
#pragma unroll
  for (int c = 0; c < Cn; ++c) {
    const float* gp = gb + (long)c * PLANE;
    for (int idx = threadIdx.x; idx < BODY_F4; idx += BLOCK) {
      const int r = idx >> 5;
      const int k = idx & 31;
      const int gh = h0 - 2 + r;
      const int ghc = min(max(gh, 0), Hn - 1);
      float4 v = *(const float4*)(gp + (long)ghc * Wn + (w0 + 4 * k));
      if (gh < 0 || gh >= Hn) v = make_float4(PADV, PADV, PADV, PADV);
      *(float4*)&tile[c][r][4 + 4 * k] = v;
    }
  }
  // ---- stage 4 halo cols: L in {2,3,132,133} = global {w0-2,w0-1,w0+128,w0+129} ----
  {
    const int idx = threadIdx.x;
    if (idx < Cn * GH * 4) {                           // 240
      const int c = idx / (GH * 4);
      const int rem = idx - c * (GH * 4);
      const int r = rem >> 2;
      const int j = rem & 3;
      const int L = (j >> 1) ? (132 + (j & 1)) : (2 + (j & 1));
      const int gcol = w0 - 4 + L;
      const int gh = h0 - 2 + r;
      const bool ok = (gh >= 0) && (gh < Hn) && (gcol >= 0) && (gcol < Wn);
      const int ghc = min(max(gh, 0), Hn - 1);
      const int gcc = min(max(gcol, 0), Wn - 1);
      tile[c][r][L] = ok ? gb[(long)c * PLANE + (long)ghc * Wn + gcc] : PADV;
    }
  }

  // ---- pred: 8 consecutive px per thread ----
  const int tx = threadIdx.x & 15;                     // 16 strips of 8 px
  const int ty = threadIdx.x >> 4;                     // 16 rows

  float p[Cn][8];
  const float* pb =
      pred + (long)b * Cn * PLANE + (long)(h0 + ty) * Wn + (w0 + 8 * tx);
#pragma unroll
  for (int c = 0; c < Cn; ++c) {
    const float4 v0 = *(const float4*)(pb + (long)c * PLANE);
    const float4 v1 = *(const float4*)(pb + (long)c * PLANE + 4);
    p[c][0] = v0.x; p[c][1] = v0.y; p[c][2] = v0.z; p[c][3] = v0.w;
    p[c][4] = v1.x; p[c][5] = v1.y; p[c][6] = v1.z; p[c][7] = v1.w;
  }

  __syncthreads();

  float m[8];
#pragma unroll
  for (int q = 0; q < 8; ++q) m[q] = 3.0e38f;

#pragma unroll
  for (int di = 0; di < 5; ++di) {
    float s[5][8];
#pragma unroll
    for (int dj = 0; dj < 5; ++dj)
#pragma unroll
      for (int q = 0; q < 8; ++q) s[dj][q] = 0.f;

#pragma unroll
    for (int c = 0; c < Cn; ++c) {
      // LDS cols 8tx .. 8tx+15 ; pixel q, shift dj -> g[q+dj+2]
      const float* base = &tile[c][ty + di][8 * tx];
      const float4 a = *(const float4*)(base);
      const float4 bq = *(const float4*)(base + 4);
      const float4 cq = *(const float4*)(base + 8);
      const float4 dq = *(const float4*)(base + 12);
      const float g[16] = {a.x,  a.y,  a.z,  a.w,  bq.x, bq.y, bq.z, bq.w,
                           cq.x, cq.y, cq.z, cq.w, dq.x, dq.y, dq.z, dq.w};
#pragma unroll
      for (int dj = 0; dj < 5; ++dj)
#pragma unroll
        for (int q = 0; q < 8; ++q)
          s[dj][q] += fabsf(g[q + dj + 2] - p[c][q]);
    }
#pragma unroll
    for (int q = 0; q < 8; ++q) {
      const float t = fminf(fminf(s[0][q], s[1][q]),
                            fminf(fminf(s[2][q], s[3][q]), s[4][q]));
      m[q] = fminf(m[q], t);
    }
  }

  float v = ((m[0] + m[1]) + (m[2] + m[3])) + ((m[4] + m[5]) + (m[6] + m[7]));

  // ---- block reduction ----
#pragma unroll
  for (int off = 32; off > 0; off >>= 1) v += __shfl_down(v, off, 64);
  __shared__ float wsum[BLOCK / 64];
  const int lane = threadIdx.x & 63;
  const int wid = threadIdx.x >> 6;
  if (lane == 0) wsum[wid] = v;
  __syncthreads();
  if (threadIdx.x == 0)
    partial[blockIdx.x] = (wsum[0] + wsum[1]) + (wsum[2] + wsum[3]);
}

__global__ __launch_bounds__(256) void nnloss_reduce(
    const float* __restrict__ partial, float* __restrict__ out) {
  double acc = 0.0;
  for (int i = threadIdx.x; i < NBLOCKS; i += 256) acc += (double)partial[i];
#pragma unroll
  for (int off = 32; off > 0; off >>= 1) acc += __shfl_down(acc, off, 64);
  __shared__ double sd[4];
  const int lane = threadIdx.x & 63;
  const int wid = threadIdx.x >> 6;
  if (lane == 0) sd[wid] = acc;
  __syncthreads();
  if (threadIdx.x == 0) {
    const double tot = (sd[0] + sd[1]) + (sd[2] + sd[3]);
    out[0] = (float)(tot / ((double)Bn * Hn * Wn));
  }
}

extern "C" void kernel_launch(void* const* d_in, const int* in_sizes, int n_in,
                              void* d_out, int out_size, void* d_ws, size_t ws_size,
                              hipStream_t stream) {
  const float* pred = (const float*)d_in[0];
  const float* gt = (const float*)d_in[1];
  // d_in[2], d_in[3] are nh=5, nw=5 (hard-coded)
  float* out = (float*)d_out;
  float* partial = (float*)d_ws;  // 2048 floats = 8 KB

  nnloss_main<<<NBLOCKS, BLOCK, 0, stream>>>(pred, gt, partial);
  nnloss_reduce<<<1, 256, 0, stream>>>(partial, out);
}

// Round 4
// 36.900 us; speedup vs baseline: 1.2273x; 1.2273x over previous
//
#include <hip/hip_runtime.h>

// NNLoss: min over 5x5 shifted neighborhoods of channel-summed L1 distance,
// then global mean. B=16, C=3, H=W=512, fp32.
// R4: fix LDS bank conflicts (GW=140, ty=tid&15 mapping -> uniform 8/bank),
// 12-float window reads (b64+b128+b128+b64), c=0 folded into s-init.

#define PADV (-10000.0f)

constexpr int Bn = 16, Cn = 3, Hn = 512, Wn = 512;
constexpr long PLANE = (long)Hn * Wn;                  // 262144

constexpr int TW = 128, TH = 16;                       // output tile per block
constexpr int GW = 140;                                // padded; used cols 0..135, global w0-4+L
constexpr int GH = TH + 4;                             // 20 rows: h0-2 .. h0+17
constexpr int BLOCK = 256;
constexpr int TILES_W = Wn / TW;                       // 4
constexpr int TILES_H = Hn / TH;                       // 32
constexpr int NBLOCKS = Bn * TILES_H * TILES_W;        // 2048
constexpr int BODY_F4 = GH * 32;                       // 640 float4 per channel (cols 4..131)

__global__ __launch_bounds__(BLOCK, 4) void nnloss_main(
    const float* __restrict__ pred, const float* __restrict__ gt,
    float* __restrict__ partial) {
  const int bid = blockIdx.x;
  const int tw = bid & (TILES_W - 1);
  const int th = (bid >> 2) & (TILES_H - 1);
  const int b = bid >> 7;
  const int w0 = tw * TW;
  const int h0 = th * TH;

  __shared__ __align__(16) float tile[Cn][GH][GW];     // 33,600 B

  const float* gb = gt + (long)b * Cn * PLANE;

  // ---- stage body: LDS cols [4,132) = global cols [w0, w0+128), float4 ----
#pragma unroll
  for (int c = 0; c < Cn; ++c) {
    const float* gp = gb + (long)c * PLANE;
#pragma unroll
    for (int m = 0; m < 3; ++m) {                      // 640 / 256 = 2.5
      const int idx = threadIdx.x + m * BLOCK;
      if (idx < BODY_F4) {
        const int r = idx >> 5;
        const int k = idx & 31;
        const int gh = h0 - 2 + r;
        const int ghc = min(max(gh, 0), Hn - 1);
        float4 v = *(const float4*)(gp + (long)ghc * Wn + (w0 + 4 * k));
        if (gh < 0 || gh >= Hn) v = make_float4(PADV, PADV, PADV, PADV);
        *(float4*)&tile[c][r][4 + 4 * k] = v;
      }
    }
  }
  // ---- stage 4 halo cols: L in {2,3,132,133} = global {w0-2,w0-1,w0+128,w0+129} ----
  {
    const int idx = threadIdx.x;
    if (idx < Cn * GH * 4) {                           // 240
      const int c = idx / (GH * 4);
      const int rem = idx - c * (GH * 4);
      const int r = rem >> 2;
      const int j = rem & 3;
      const int L = (j >> 1) ? (132 + (j & 1)) : (2 + (j & 1));
      const int gcol = w0 - 4 + L;
      const int gh = h0 - 2 + r;
      const bool ok = (gh >= 0) && (gh < Hn) && (gcol >= 0) && (gcol < Wn);
      const int ghc = min(max(gh, 0), Hn - 1);
      const int gcc = min(max(gcol, 0), Wn - 1);
      tile[c][r][L] = ok ? gb[(long)c * PLANE + (long)ghc * Wn + gcc] : PADV;
    }
  }

  // ---- pred: 8 consecutive px per thread; ty fast (bank spread) ----
  const int ty = threadIdx.x & 15;                     // row within tile
  const int tx = threadIdx.x >> 4;                     // 16 strips of 8 px

  float p[Cn][8];
  const float* pb =
      pred + (long)b * Cn * PLANE + (long)(h0 + ty) * Wn + (w0 + 8 * tx);
#pragma unroll
  for (int c = 0; c < Cn; ++c) {
    const float4 v0 = *(const float4*)(pb + (long)c * PLANE);
    const float4 v1 = *(const float4*)(pb + (long)c * PLANE + 4);
    p[c][0] = v0.x; p[c][1] = v0.y; p[c][2] = v0.z; p[c][3] = v0.w;
    p[c][4] = v1.x; p[c][5] = v1.y; p[c][6] = v1.z; p[c][7] = v1.w;
  }

  __syncthreads();

  float m[8];
#pragma unroll
  for (int q = 0; q < 8; ++q) m[q] = 3.0e38f;

#pragma unroll
  for (int di = 0; di < 5; ++di) {
    float s[5][8];
    float g[16];
    // channel 0: assign (no zero-init), channels 1,2: accumulate
#pragma unroll
    for (int c = 0; c < Cn; ++c) {
      const float* base = &tile[c][ty + di][8 * tx];
      const float2 e0 = *(const float2*)(base + 2);
      const float4 A = *(const float4*)(base + 4);
      const float4 Bq = *(const float4*)(base + 8);
      const float2 e1 = *(const float2*)(base + 12);
      g[2] = e0.x;  g[3] = e0.y;
      g[4] = A.x;   g[5] = A.y;   g[6] = A.z;   g[7] = A.w;
      g[8] = Bq.x;  g[9] = Bq.y;  g[10] = Bq.z; g[11] = Bq.w;
      g[12] = e1.x; g[13] = e1.y;
      if (c == 0) {
#pragma unroll
        for (int dj = 0; dj < 5; ++dj)
#pragma unroll
          for (int q = 0; q < 8; ++q)
            s[dj][q] = fabsf(g[q + dj + 2] - p[0][q]);
      } else {
#pragma unroll
        for (int dj = 0; dj < 5; ++dj)
#pragma unroll
          for (int q = 0; q < 8; ++q)
            s[dj][q] += fabsf(g[q + dj + 2] - p[c][q]);
      }
    }
#pragma unroll
    for (int q = 0; q < 8; ++q) {
      const float t = fminf(fminf(s[0][q], s[1][q]),
                            fminf(fminf(s[2][q], s[3][q]), s[4][q]));
      m[q] = fminf(m[q], t);
    }
  }

  float v = ((m[0] + m[1]) + (m[2] + m[3])) + ((m[4] + m[5]) + (m[6] + m[7]));

  // ---- block reduction ----
#pragma unroll
  for (int off = 32; off > 0; off >>= 1) v += __shfl_down(v, off, 64);
  __shared__ float wsum[BLOCK / 64];
  const int lane = threadIdx.x & 63;
  const int wid = threadIdx.x >> 6;
  if (lane == 0) wsum[wid] = v;
  __syncthreads();
  if (threadIdx.x == 0)
    partial[blockIdx.x] = (wsum[0] + wsum[1]) + (wsum[2] + wsum[3]);
}

__global__ __launch_bounds__(256) void nnloss_reduce(
    const float* __restrict__ partial, float* __restrict__ out) {
  double acc = 0.0;
  for (int i = threadIdx.x; i < NBLOCKS; i += 256) acc += (double)partial[i];
#pragma unroll
  for (int off = 32; off > 0; off >>= 1) acc += __shfl_down(acc, off, 64);
  __shared__ double sd[4];
  const int lane = threadIdx.x & 63;
  const int wid = threadIdx.x >> 6;
  if (lane == 0) sd[wid] = acc;
  __syncthreads();
  if (threadIdx.x == 0) {
    const double tot = (sd[0] + sd[1]) + (sd[2] + sd[3]);
    out[0] = (float)(tot / ((double)Bn * Hn * Wn));
  }
}

extern "C" void kernel_launch(void* const* d_in, const int* in_sizes, int n_in,
                              void* d_out, int out_size, void* d_ws, size_t ws_size,
                              hipStream_t stream) {
  const float* pred = (const float*)d_in[0];
  const float* gt = (const float*)d_in[1];
  // d_in[2], d_in[3] are nh=5, nw=5 (hard-coded)
  float* out = (float*)d_out;
  float* partial = (float*)d_ws;  // 2048 floats = 8 KB

  nnloss_main<<<NBLOCKS, BLOCK, 0, stream>>>(pred, gt, partial);
  nnloss_reduce<<<1, 256, 0, stream>>>(partial, out);
}

// Round 5
// 36.397 us; speedup vs baseline: 1.2443x; 1.0138x over previous
//
#include <hip/hip_runtime.h>

// NNLoss: min over 5x5 shifted neighborhoods of channel-summed L1 distance,
// then global mean. B=16, C=3, H=W=512, fp32.
// R5: 512-thread blocks, 4 px/thread -> 32 waves/CU occupancy cap (was 16).
// GW=140 conflict-free geometry kept; 10-float windows (b128+b128+b64);
// min3-fusable reduction; __launch_bounds__(512,8) caps VGPR at 64.

#define PADV (-10000.0f)

constexpr int Bn = 16, Cn = 3, Hn = 512, Wn = 512;
constexpr long PLANE = (long)Hn * Wn;                  // 262144

constexpr int TW = 128, TH = 16;                       // output tile per block
constexpr int GW = 140;                                // padded; used cols 0..133
constexpr int GH = TH + 4;                             // 20 rows: h0-2 .. h0+17
constexpr int BLOCK = 512;
constexpr int TILES_W = Wn / TW;                       // 4
constexpr int TILES_H = Hn / TH;                       // 32
constexpr int NBLOCKS = Bn * TILES_H * TILES_W;        // 2048
constexpr int BODY_F4 = GH * 32;                       // 640 float4 per channel

__global__ __launch_bounds__(BLOCK, 8) void nnloss_main(
    const float* __restrict__ pred, const float* __restrict__ gt,
    float* __restrict__ partial) {
  const int bid = blockIdx.x;
  const int tw = bid & (TILES_W - 1);
  const int th = (bid >> 2) & (TILES_H - 1);
  const int b = bid >> 7;
  const int w0 = tw * TW;
  const int h0 = th * TH;

  __shared__ __align__(16) float tile[Cn][GH][GW];     // 33,600 B

  const float* gb = gt + (long)b * Cn * PLANE;

  // ---- stage body: LDS cols [4,132) = global cols [w0, w0+128), float4 ----
#pragma unroll
  for (int c = 0; c < Cn; ++c) {
    const float* gp = gb + (long)c * PLANE;
#pragma unroll
    for (int m = 0; m < 2; ++m) {                      // 640 over 512 threads
      const int idx = threadIdx.x + m * BLOCK;
      if (idx < BODY_F4) {
        const int r = idx >> 5;
        const int k = idx & 31;
        const int gh = h0 - 2 + r;
        const int ghc = min(max(gh, 0), Hn - 1);
        float4 v = *(const float4*)(gp + (long)ghc * Wn + (w0 + 4 * k));
        if (gh < 0 || gh >= Hn) v = make_float4(PADV, PADV, PADV, PADV);
        *(float4*)&tile[c][r][4 + 4 * k] = v;
      }
    }
  }
  // ---- stage 4 halo cols: L in {2,3,132,133} ----
  {
    const int idx = threadIdx.x;
    if (idx < Cn * GH * 4) {                           // 240
      const int c = idx / (GH * 4);
      const int rem = idx - c * (GH * 4);
      const int r = rem >> 2;
      const int j = rem & 3;
      const int L = (j >> 1) ? (132 + (j & 1)) : (2 + (j & 1));
      const int gcol = w0 - 4 + L;
      const int gh = h0 - 2 + r;
      const bool ok = (gh >= 0) && (gh < Hn) && (gcol >= 0) && (gcol < Wn);
      const int ghc = min(max(gh, 0), Hn - 1);
      const int gcc = min(max(gcol, 0), Wn - 1);
      tile[c][r][L] = ok ? gb[(long)c * PLANE + (long)ghc * Wn + gcc] : PADV;
    }
  }

  // ---- pred: 4 consecutive px per thread; ty fast (bank spread) ----
  const int ty = threadIdx.x & 15;                     // row within tile
  const int tx = threadIdx.x >> 4;                     // 32 strips of 4 px

  float p[Cn][4];
  const float* pb =
      pred + (long)b * Cn * PLANE + (long)(h0 + ty) * Wn + (w0 + 4 * tx);
#pragma unroll
  for (int c = 0; c < Cn; ++c) {
    const float4 v = *(const float4*)(pb + (long)c * PLANE);
    p[c][0] = v.x; p[c][1] = v.y; p[c][2] = v.z; p[c][3] = v.w;
  }

  __syncthreads();

  float m4[4] = {3.0e38f, 3.0e38f, 3.0e38f, 3.0e38f};

#pragma unroll
  for (int di = 0; di < 5; ++di) {
    float s[5][4];
    float g[10];
#pragma unroll
    for (int c = 0; c < Cn; ++c) {
      // window: LDS cols 4tx+2 .. 4tx+9 ; pixel q, shift dj -> g[q+dj+2]
      const float* base = &tile[c][ty + di][4 * tx];
      const float4 A = *(const float4*)(base);
      const float4 Bq = *(const float4*)(base + 4);
      const float2 Cq = *(const float2*)(base + 8);
      g[0] = A.x;  g[1] = A.y;  g[2] = A.z;  g[3] = A.w;
      g[4] = Bq.x; g[5] = Bq.y; g[6] = Bq.z; g[7] = Bq.w;
      g[8] = Cq.x; g[9] = Cq.y;
      if (c == 0) {
#pragma unroll
        for (int dj = 0; dj < 5; ++dj)
#pragma unroll
          for (int q = 0; q < 4; ++q)
            s[dj][q] = fabsf(g[q + dj + 2] - p[0][q]);
      } else {
#pragma unroll
        for (int dj = 0; dj < 5; ++dj)
#pragma unroll
          for (int q = 0; q < 4; ++q)
            s[dj][q] += fabsf(g[q + dj + 2] - p[c][q]);
      }
    }
#pragma unroll
    for (int q = 0; q < 4; ++q) {
      const float t1 = fminf(fminf(s[0][q], s[1][q]), s[2][q]);   // v_min3
      const float t2 = fminf(fminf(t1, s[3][q]), s[4][q]);        // v_min3
      m4[q] = fminf(m4[q], t2);
    }
  }

  float v = (m4[0] + m4[1]) + (m4[2] + m4[3]);

  // ---- block reduction ----
#pragma unroll
  for (int off = 32; off > 0; off >>= 1) v += __shfl_down(v, off, 64);
  __shared__ float wsum[BLOCK / 64];
  const int lane = threadIdx.x & 63;
  const int wid = threadIdx.x >> 6;
  if (lane == 0) wsum[wid] = v;
  __syncthreads();
  if (threadIdx.x == 0) {
    float t = 0.f;
#pragma unroll
    for (int i = 0; i < BLOCK / 64; ++i) t += wsum[i];
    partial[blockIdx.x] = t;
  }
}

__global__ __launch_bounds__(256) void nnloss_reduce(
    const float* __restrict__ partial, float* __restrict__ out) {
  double acc = 0.0;
  for (int i = threadIdx.x; i < NBLOCKS; i += 256) acc += (double)partial[i];
#pragma unroll
  for (int off = 32; off > 0; off >>= 1) acc += __shfl_down(acc, off, 64);
  __shared__ double sd[4];
  const int lane = threadIdx.x & 63;
  const int wid = threadIdx.x >> 6;
  if (lane == 0) sd[wid] = acc;
  __syncthreads();
  if (threadIdx.x == 0) {
    const double tot = (sd[0] + sd[1]) + (sd[2] + sd[3]);
    out[0] = (float)(tot / ((double)Bn * Hn * Wn));
  }
}

extern "C" void kernel_launch(void* const* d_in, const int* in_sizes, int n_in,
                              void* d_out, int out_size, void* d_ws, size_t ws_size,
                              hipStream_t stream) {
  const float* pred = (const float*)d_in[0];
  const float* gt = (const float*)d_in[1];
  // d_in[2], d_in[3] are nh=5, nw=5 (hard-coded)
  float* out = (float*)d_out;
  float* partial = (float*)d_ws;  // 2048 floats = 8 KB

  nnloss_main<<<NBLOCKS, BLOCK, 0, stream>>>(pred, gt, partial);
  nnloss_reduce<<<1, 256, 0, stream>>>(partial, out);
}

// Round 6
// 35.825 us; speedup vs baseline: 1.2642x; 1.0160x over previous
//
#include <hip/hip_runtime.h>

// NNLoss: min over 5x5 shifted neighborhoods of channel-summed L1 distance,
// then global mean. B=16, C=3, H=W=512, fp32.
// R6: each thread owns 4px x 2 output rows -> each LDS row read once per
// channel, serving both (row,di) pairs from registers. LDS reads 11.25/px ->
// 6.75/px. Tile 128x16, GW=140 (bank-balanced), 256 thr, 4 blocks/CU.

#define PADV (-10000.0f)

constexpr int Bn = 16, Cn = 3, Hn = 512, Wn = 512;
constexpr long PLANE = (long)Hn * Wn;                  // 262144

constexpr int TW = 128, TH = 16;                       // output tile per block
constexpr int GW = 140;                                // padded; used cols 0..133
constexpr int GH = TH + 4;                             // 20 rows: h0-2 .. h0+17
constexpr int BLOCK = 256;
constexpr int TILES_W = Wn / TW;                       // 4
constexpr int TILES_H = Hn / TH;                       // 32
constexpr int NBLOCKS = Bn * TILES_H * TILES_W;        // 2048
constexpr int BODY_F4 = GH * 32;                       // 640 float4 per channel

__global__ __launch_bounds__(BLOCK, 4) void nnloss_main(
    const float* __restrict__ pred, const float* __restrict__ gt,
    float* __restrict__ partial) {
  const int bid = blockIdx.x;
  const int tw = bid & (TILES_W - 1);
  const int th = (bid >> 2) & (TILES_H - 1);
  const int b = bid >> 7;
  const int w0 = tw * TW;
  const int h0 = th * TH;

  __shared__ __align__(16) float tile[Cn][GH][GW];     // 33,600 B

  const float* gb = gt + (long)b * Cn * PLANE;

  // ---- stage body: LDS cols [4,132) = global cols [w0, w0+128), float4 ----
#pragma unroll
  for (int c = 0; c < Cn; ++c) {
    const float* gp = gb + (long)c * PLANE;
#pragma unroll
    for (int m = 0; m < 3; ++m) {                      // 640 over 256 threads
      const int idx = threadIdx.x + m * BLOCK;
      if (idx < BODY_F4) {
        const int r = idx >> 5;
        const int k = idx & 31;
        const int gh = h0 - 2 + r;
        const int ghc = min(max(gh, 0), Hn - 1);
        float4 v = *(const float4*)(gp + (long)ghc * Wn + (w0 + 4 * k));
        if (gh < 0 || gh >= Hn) v = make_float4(PADV, PADV, PADV, PADV);
        *(float4*)&tile[c][r][4 + 4 * k] = v;
      }
    }
  }
  // ---- stage 4 halo cols: L in {2,3,132,133} ----
  {
    const int idx = threadIdx.x;
    if (idx < Cn * GH * 4) {                           // 240
      const int c = idx / (GH * 4);
      const int rem = idx - c * (GH * 4);
      const int r = rem >> 2;
      const int j = rem & 3;
      const int L = (j >> 1) ? (132 + (j & 1)) : (2 + (j & 1));
      const int gcol = w0 - 4 + L;
      const int gh = h0 - 2 + r;
      const bool ok = (gh >= 0) && (gh < Hn) && (gcol >= 0) && (gcol < Wn);
      const int ghc = min(max(gh, 0), Hn - 1);
      const int gcc = min(max(gcol, 0), Wn - 1);
      tile[c][r][L] = ok ? gb[(long)c * PLANE + (long)ghc * Wn + gcc] : PADV;
    }
  }

  // ---- thread -> 4 px wide x 2 output rows ----
  const int tx = threadIdx.x & 31;                     // 32 strips of 4 px
  const int tyg = threadIdx.x >> 5;                    // 8 groups of 2 rows
  const int row0 = 2 * tyg;                            // tile-relative out row

  float p[2][Cn][4];
  {
    const float* pb0 =
        pred + (long)b * Cn * PLANE + (long)(h0 + row0) * Wn + (w0 + 4 * tx);
#pragma unroll
    for (int r = 0; r < 2; ++r)
#pragma unroll
      for (int c = 0; c < Cn; ++c) {
        const float4 v = *(const float4*)(pb0 + (long)c * PLANE + (long)r * Wn);
        p[r][c][0] = v.x; p[r][c][1] = v.y; p[r][c][2] = v.z; p[r][c][3] = v.w;
      }
  }

  __syncthreads();

  float mm[2][4];
#pragma unroll
  for (int r = 0; r < 2; ++r)
#pragma unroll
    for (int q = 0; q < 4; ++q) mm[r][q] = 3.0e38f;

  // LDS rows row0 .. row0+5 each read once per channel; row (row0+rowIdx)
  // serves output row r with di = rowIdx - r (valid di in [0,4]).
#pragma unroll
  for (int rowIdx = 0; rowIdx < 6; ++rowIdx) {
    const int lr = row0 + rowIdx;
    float g[Cn][10];
#pragma unroll
    for (int c = 0; c < Cn; ++c) {
      const float* base = &tile[c][lr][4 * tx];
      const float4 A = *(const float4*)(base);
      const float4 Bq = *(const float4*)(base + 4);
      const float2 Cq = *(const float2*)(base + 8);
      g[c][0] = A.x;  g[c][1] = A.y;  g[c][2] = A.z;  g[c][3] = A.w;
      g[c][4] = Bq.x; g[c][5] = Bq.y; g[c][6] = Bq.z; g[c][7] = Bq.w;
      g[c][8] = Cq.x; g[c][9] = Cq.y;
    }
#pragma unroll
    for (int r = 0; r < 2; ++r) {
      const int di = rowIdx - r;
      if (di < 0 || di > 4) continue;                  // compile-time pruned
      float s[5][4];
#pragma unroll
      for (int dj = 0; dj < 5; ++dj)
#pragma unroll
        for (int q = 0; q < 4; ++q)
          s[dj][q] = fabsf(g[0][q + dj + 2] - p[r][0][q]);
#pragma unroll
      for (int c = 1; c < Cn; ++c)
#pragma unroll
        for (int dj = 0; dj < 5; ++dj)
#pragma unroll
          for (int q = 0; q < 4; ++q)
            s[dj][q] += fabsf(g[c][q + dj + 2] - p[r][c][q]);
#pragma unroll
      for (int q = 0; q < 4; ++q) {
        const float t1 = fminf(fminf(s[0][q], s[1][q]), s[2][q]);  // v_min3
        const float t2 = fminf(fminf(t1, s[3][q]), s[4][q]);       // v_min3
        mm[r][q] = fminf(mm[r][q], t2);
      }
    }
  }

  float v = ((mm[0][0] + mm[0][1]) + (mm[0][2] + mm[0][3])) +
            ((mm[1][0] + mm[1][1]) + (mm[1][2] + mm[1][3]));

  // ---- block reduction ----
#pragma unroll
  for (int off = 32; off > 0; off >>= 1) v += __shfl_down(v, off, 64);
  __shared__ float wsum[BLOCK / 64];
  const int lane = threadIdx.x & 63;
  const int wid = threadIdx.x >> 6;
  if (lane == 0) wsum[wid] = v;
  __syncthreads();
  if (threadIdx.x == 0)
    partial[blockIdx.x] = (wsum[0] + wsum[1]) + (wsum[2] + wsum[3]);
}

__global__ __launch_bounds__(256) void nnloss_reduce(
    const float* __restrict__ partial, float* __restrict__ out) {
  double acc = 0.0;
  for (int i = threadIdx.x; i < NBLOCKS; i += 256) acc += (double)partial[i];
#pragma unroll
  for (int off = 32; off > 0; off >>= 1) acc += __shfl_down(acc, off, 64);
  __shared__ double sd[4];
  const int lane = threadIdx.x & 63;
  const int wid = threadIdx.x >> 6;
  if (lane == 0) sd[wid] = acc;
  __syncthreads();
  if (threadIdx.x == 0) {
    const double tot = (sd[0] + sd[1]) + (sd[2] + sd[3]);
    out[0] = (float)(tot / ((double)Bn * Hn * Wn));
  }
}

extern "C" void kernel_launch(void* const* d_in, const int* in_sizes, int n_in,
                              void* d_out, int out_size, void* d_ws, size_t ws_size,
                              hipStream_t stream) {
  const float* pred = (const float*)d_in[0];
  const float* gt = (const float*)d_in[1];
  // d_in[2], d_in[3] are nh=5, nw=5 (hard-coded)
  float* out = (float*)d_out;
  float* partial = (float*)d_ws;  // 2048 floats = 8 KB

  nnloss_main<<<NBLOCKS, BLOCK, 0, stream>>>(pred, gt, partial);
  nnloss_reduce<<<1, 256, 0, stream>>>(partial, out);
}